// Round 11
// baseline (18144.926 us; speedup 1.0000x reference)
//
#include <hip/hip_runtime.h>

// Problem constants
#define BB 64       // batch
#define TT 512      // time steps
#define II 128      // input dim
#define HH 512      // hidden
#define CC 5        // out classes

// ---------------------------------------------------------------------------
// GEMM (layer-0 input projection only)
// ---------------------------------------------------------------------------
__global__ __launch_bounds__(256) void gemm_bias_kernel(
    const float* __restrict__ A, const float* __restrict__ W,
    const float* __restrict__ b1, const float* __restrict__ b2,
    float* __restrict__ out, int K)
{
    __shared__ float As[16][132];
    __shared__ float Bs[16][132];
    const int tid = threadIdx.x;
    const int bm = blockIdx.x;
    const int bn = blockIdx.y;
    const int tx = tid & 15;
    const int ty = tid >> 4;
    const int lr = tid >> 2;
    const int lk = (tid & 3) << 2;

    const float* Ab = A + (size_t)bm * 128 * K;
    const float* Wb = W + (size_t)bn * 128 * K;

    float acc[8][8];
#pragma unroll
    for (int i = 0; i < 8; ++i)
#pragma unroll
        for (int j = 0; j < 8; ++j) acc[i][j] = 0.f;

    for (int k0 = 0; k0 < K; k0 += 16) {
        float4 a0 = *(const float4*)(Ab + (size_t)lr * K + k0 + lk);
        float4 a1 = *(const float4*)(Ab + (size_t)(lr + 64) * K + k0 + lk);
        float4 w0 = *(const float4*)(Wb + (size_t)lr * K + k0 + lk);
        float4 w1 = *(const float4*)(Wb + (size_t)(lr + 64) * K + k0 + lk);
        __syncthreads();
        As[lk + 0][lr] = a0.x; As[lk + 1][lr] = a0.y; As[lk + 2][lr] = a0.z; As[lk + 3][lr] = a0.w;
        As[lk + 0][lr + 64] = a1.x; As[lk + 1][lr + 64] = a1.y; As[lk + 2][lr + 64] = a1.z; As[lk + 3][lr + 64] = a1.w;
        Bs[lk + 0][lr] = w0.x; Bs[lk + 1][lr] = w0.y; Bs[lk + 2][lr] = w0.z; Bs[lk + 3][lr] = w0.w;
        Bs[lk + 0][lr + 64] = w1.x; Bs[lk + 1][lr + 64] = w1.y; Bs[lk + 2][lr + 64] = w1.z; Bs[lk + 3][lr + 64] = w1.w;
        __syncthreads();
#pragma unroll
        for (int k = 0; k < 16; ++k) {
            float4 av0 = *(const float4*)&As[k][ty * 8];
            float4 av1 = *(const float4*)&As[k][ty * 8 + 4];
            float4 bv0 = *(const float4*)&Bs[k][tx * 8];
            float4 bv1 = *(const float4*)&Bs[k][tx * 8 + 4];
            float a[8] = {av0.x, av0.y, av0.z, av0.w, av1.x, av1.y, av1.z, av1.w};
            float b[8] = {bv0.x, bv0.y, bv0.z, bv0.w, bv1.x, bv1.y, bv1.z, bv1.w};
#pragma unroll
            for (int i = 0; i < 8; ++i)
#pragma unroll
                for (int j = 0; j < 8; ++j)
                    acc[i][j] = fmaf(a[i], b[j], acc[i][j]);
        }
    }

    const int nb = bn * 128 + tx * 8;
    float bias[8];
#pragma unroll
    for (int j = 0; j < 8; ++j) bias[j] = b1[nb + j] + b2[nb + j];
#pragma unroll
    for (int i = 0; i < 8; ++i) {
        const size_t m = (size_t)bm * 128 + ty * 8 + i;
        float4 o0 = {acc[i][0] + bias[0], acc[i][1] + bias[1], acc[i][2] + bias[2], acc[i][3] + bias[3]};
        float4 o1 = {acc[i][4] + bias[4], acc[i][5] + bias[5], acc[i][6] + bias[6], acc[i][7] + bias[7]};
        *(float4*)(out + m * HH + nb) = o0;
        *(float4*)(out + m * HH + nb + 4) = o1;
    }
}

// ---------------------------------------------------------------------------
// R11: fused 3-layer wavefront pipeline re-tiled for the OBSERVED 128-VGPR
// allocator ceiling (R10 spilled: demand ~230, got 128, FETCH 3.8GB).
// 192 blocks x 512 threads: bx = l*64 + s*4 + g
//   l=layer(3), s=slice(16 x 32 rows), g=group(4 x 16 batches).
// lane = rloc*16 + kseg: rloc=lane>>4 (4 rows/wave), kseg=lane&15 (32-float
// K-chunk). W slices: hh 8 float4 + ih 8 float4 = 64 VGPR. accs 16. xp via
// LDS staging (XPB) not regs. Total demand ~115 < 128 -> no spill (verify:
// FETCH_SIZE must be ~0.1GB, not GB).
// Protocol identical to R10 (which PASSED): obuf 4 slots + sign-phase
// 1^(((q-1)>>2)&1), per-wave written[] LDS gate, self-bypass, slack-vmem-
// before-poll; pbuf 64-ring epoch 1^((t>>6)&1), acks every 16 steps with
// gap<=47<64. LDS chunk stride 36 floats (16B-aligned; banks 4k%32 -> 2-way
// max = free). Capacity: LDS 151.6KB -> 1 block/CU, 192 <= 256 CUs -> all
// resident -> spins deadlock-free.
// ---------------------------------------------------------------------------
#define CSTR 36                 // chunk stride (floats)
#define BSTR (16 * CSTR)        // batch stride = 576

__global__ __launch_bounds__(512)
__attribute__((amdgpu_waves_per_eu(2, 2)))
void rnn_pipeline_kernel(
    const float* __restrict__ XP,
    const float* __restrict__ Whh0, const float* __restrict__ Whh1,
    const float* __restrict__ Whh2,
    const float* __restrict__ Wih1, const float* __restrict__ Wih2,
    const float* __restrict__ bi1, const float* __restrict__ bh1,
    const float* __restrict__ bi2, const float* __restrict__ bh2,
    float* __restrict__ yfinal,
    unsigned long long* obuf, unsigned long long* pbuf, int* ack)
{
    __shared__ float HY[2][16][BSTR / 16 * 16];   // [slot][batch][chunk*36+j] 73.7KB
    __shared__ float PY[2][16][BSTR / 16 * 16];   // 73.7KB
    __shared__ float XPB[2][512];                 // xp staging (l==0) 4KB
    __shared__ int written[8];

    const int tid  = threadIdx.x;
    const int bx   = blockIdx.x;
    const int l    = bx >> 6;          // layer 0..2
    const int s    = (bx >> 2) & 15;   // slice 0..15 (rows s*32..+31)
    const int g    = bx & 3;           // group 0..3 (batches g*16..+15)
    const int lane = tid & 63;
    const int wv   = tid >> 6;
    const int rloc = lane >> 4;        // 0..3
    const int kseg = lane & 15;        // 0..15 -> k in [kseg*32, kseg*32+32)
    const int rl   = wv * 4 + rloc;    // local row 0..31
    const int R    = s * 32 + rl;      // global row

    const float* Whh = (l == 0) ? Whh0 : ((l == 1) ? Whh1 : Whh2);
    const float* Wih = (l == 2) ? Wih2 : Wih1;   // l==0: valid mem, unused
    const float* wr = Whh + (size_t)R * HH + kseg * 32;
    const float* vr = Wih + (size_t)R * HH + kseg * 32;

    const float4 w0 = *(const float4*)(wr + 0);
    const float4 w1 = *(const float4*)(wr + 4);
    const float4 w2 = *(const float4*)(wr + 8);
    const float4 w3 = *(const float4*)(wr + 12);
    const float4 w4 = *(const float4*)(wr + 16);
    const float4 w5 = *(const float4*)(wr + 20);
    const float4 w6 = *(const float4*)(wr + 24);
    const float4 w7 = *(const float4*)(wr + 28);
    const float4 v0 = *(const float4*)(vr + 0);
    const float4 v1 = *(const float4*)(vr + 4);
    const float4 v2 = *(const float4*)(vr + 8);
    const float4 v3 = *(const float4*)(vr + 12);
    const float4 v4 = *(const float4*)(vr + 16);
    const float4 v5 = *(const float4*)(vr + 20);
    const float4 v6 = *(const float4*)(vr + 24);
    const float4 v7 = *(const float4*)(vr + 28);

    // obuf: per (l,g) 4 slots x 512 rows x 8 u64
    unsigned long long* ob  = obuf + (size_t)(l * 4 + g) * 16384;
    // pbuf: per (iface,g) 64 slots x 512 rows x 8 u64
    unsigned long long* pbw = pbuf + (size_t)((l < 2 ? l : 0) * 4 + g) * 262144;
    unsigned long long* pbr = pbuf + (size_t)((l > 0 ? l - 1 : 0) * 4 + g) * 262144;
    int* ackr = ack + ((l < 2 ? l : 0) * 4 + g) * 16;            // producer reads 16
    int* ackw = ack + ((l > 0 ? l - 1 : 0) * 4 + g) * 16 + s;    // consumer writes

    const int  ldsw    = (tid >> 5) * CSTR + (tid & 31);  // delivery idx for row tid
    const int  selfw   = s * CSTR + rl;                   // own row R
    const bool pub     = (kseg == 0);
    const bool selfrow = ((tid >> 5) == s);

    float bias = 0.f;
    if (pub && l == 1) bias = bi1[R] + bh1[R];
    if (pub && l == 2) bias = bi2[R] + bh2[R];

#pragma unroll
    for (int b = 0; b < 16; ++b) HY[0][b][ldsw] = 0.f;
    if (tid < 8) written[tid] = 0;
    if (l == 0)
        XPB[0][tid] = XP[((size_t)(g * 16 + (tid >> 5)) * TT + 0) * HH + s * 32 + (tid & 31)];
    __syncthreads();   // one-time: LDS init visible

#define PK(lo, hi, ph) ((unsigned long long)(__float_as_uint(lo) | ((ph) << 31)) | \
                        ((unsigned long long)(__float_as_uint(hi) | ((ph) << 31)) << 32))
#define BAD(u, ph) ((((unsigned)((u) >> 31) & 1u) ^ (ph)) | (((unsigned)((u) >> 63)) ^ (ph)))
#define UNP(ARR, SL, J, u) \
    ARR[SL][2*(J)][ldsw]   = __uint_as_float((unsigned)(u) & 0x7fffffffu); \
    ARR[SL][2*(J)+1][ldsw] = __uint_as_float((unsigned)((u) >> 32) & 0x7fffffffu);

    // prologue: y_{l-1}[0] (slot 0, epoch sign = 1)
    if (l > 0) {
        unsigned long long* pp = pbr + (size_t)tid * 8;
        unsigned long long u0, u1, u2, u3, u4, u5, u6, u7;
        for (;;) {
            u0 = __hip_atomic_load(pp + 0, __ATOMIC_RELAXED, __HIP_MEMORY_SCOPE_AGENT);
            u1 = __hip_atomic_load(pp + 1, __ATOMIC_RELAXED, __HIP_MEMORY_SCOPE_AGENT);
            u2 = __hip_atomic_load(pp + 2, __ATOMIC_RELAXED, __HIP_MEMORY_SCOPE_AGENT);
            u3 = __hip_atomic_load(pp + 3, __ATOMIC_RELAXED, __HIP_MEMORY_SCOPE_AGENT);
            u4 = __hip_atomic_load(pp + 4, __ATOMIC_RELAXED, __HIP_MEMORY_SCOPE_AGENT);
            u5 = __hip_atomic_load(pp + 5, __ATOMIC_RELAXED, __HIP_MEMORY_SCOPE_AGENT);
            u6 = __hip_atomic_load(pp + 6, __ATOMIC_RELAXED, __HIP_MEMORY_SCOPE_AGENT);
            u7 = __hip_atomic_load(pp + 7, __ATOMIC_RELAXED, __HIP_MEMORY_SCOPE_AGENT);
            if ((BAD(u0,1u)|BAD(u1,1u)|BAD(u2,1u)|BAD(u3,1u)|
                 BAD(u4,1u)|BAD(u5,1u)|BAD(u6,1u)|BAD(u7,1u)) == 0u) break;
        }
        UNP(PY, 0, 0, u0) UNP(PY, 0, 1, u1) UNP(PY, 0, 2, u2) UNP(PY, 0, 3, u3)
        UNP(PY, 0, 4, u4) UNP(PY, 0, 5, u5) UNP(PY, 0, 6, u6) UNP(PY, 0, 7, u7)
    }

#define FMA4(ACC, WQ, HQ) \
    ACC = fmaf(WQ.x, HQ.x, ACC); ACC = fmaf(WQ.y, HQ.y, ACC); \
    ACC = fmaf(WQ.z, HQ.z, ACC); ACC = fmaf(WQ.w, HQ.w, ACC);
#define DOT32(ACC, BASE, W) do { \
    const float* _p = (BASE); \
    float4 h0 = *(const float4*)(_p);      float4 h1 = *(const float4*)(_p + 4); \
    float4 h2 = *(const float4*)(_p + 8);  float4 h3 = *(const float4*)(_p + 12); \
    float4 h4 = *(const float4*)(_p + 16); float4 h5 = *(const float4*)(_p + 20); \
    float4 h6 = *(const float4*)(_p + 24); float4 h7 = *(const float4*)(_p + 28); \
    FMA4(ACC, W##0, h0) FMA4(ACC, W##1, h1) FMA4(ACC, W##2, h2) FMA4(ACC, W##3, h3) \
    FMA4(ACC, W##4, h4) FMA4(ACC, W##5, h5) FMA4(ACC, W##6, h6) FMA4(ACC, W##7, h7) \
} while (0)
#define BFLY(A) { A += __shfl_xor(A, 1); A += __shfl_xor(A, 2); \
                  A += __shfl_xor(A, 4); A += __shfl_xor(A, 8); }

    for (int t = 0; t < TT; ++t) {
        // (A) gate: all 8 waves delivered h[t] (and PY[t])
        if (t > 0) {
            for (;;) {
                int m = __hip_atomic_load(&written[0], __ATOMIC_RELAXED, __HIP_MEMORY_SCOPE_WORKGROUP);
#pragma unroll
                for (int c = 1; c < 8; ++c) {
                    int wc = __hip_atomic_load(&written[c], __ATOMIC_RELAXED, __HIP_MEMORY_SCOPE_WORKGROUP);
                    m = (wc < m) ? wc : m;
                }
                if (m >= t) break;
            }
            __threadfence_block();
        }
        if (l > 0 && tid == 0 && (t & 15) == 0)
            __hip_atomic_store(ackw, t, __ATOMIC_RELAXED, __HIP_MEMORY_SCOPE_AGENT);
        if (l < 2 && t > 0 && (t & 15) == 0) {
            for (;;) {
                int m = __hip_atomic_load(ackr, __ATOMIC_RELAXED, __HIP_MEMORY_SCOPE_AGENT);
#pragma unroll
                for (int c = 1; c < 16; ++c) {
                    int a = __hip_atomic_load(ackr + c, __ATOMIC_RELAXED, __HIP_MEMORY_SCOPE_AGENT);
                    m = (a < m) ? a : m;
                }
                if (m >= t - 31) break;
            }
        }

        // (B) matmuls: 16 batches; hh always, ih for l>0
        const int sl = t & 1;
        float A0=0.f,A1=0.f,A2=0.f,A3=0.f,A4=0.f,A5=0.f,A6=0.f,A7=0.f;
        float A8=0.f,A9=0.f,A10=0.f,A11=0.f,A12=0.f,A13=0.f,A14=0.f,A15=0.f;
        {
            const float* hb = &HY[sl][0][kseg * 32 + kseg * (CSTR - 32)]; // kseg*CSTR
            DOT32(A0,  hb + 0*BSTR,  w); DOT32(A1,  hb + 1*BSTR,  w);
            DOT32(A2,  hb + 2*BSTR,  w); DOT32(A3,  hb + 3*BSTR,  w);
            DOT32(A4,  hb + 4*BSTR,  w); DOT32(A5,  hb + 5*BSTR,  w);
            DOT32(A6,  hb + 6*BSTR,  w); DOT32(A7,  hb + 7*BSTR,  w);
            DOT32(A8,  hb + 8*BSTR,  w); DOT32(A9,  hb + 9*BSTR,  w);
            DOT32(A10, hb + 10*BSTR, w); DOT32(A11, hb + 11*BSTR, w);
            DOT32(A12, hb + 12*BSTR, w); DOT32(A13, hb + 13*BSTR, w);
            DOT32(A14, hb + 14*BSTR, w); DOT32(A15, hb + 15*BSTR, w);
        }
        if (l > 0) {
            const float* pbv = &PY[sl][0][kseg * CSTR];
            DOT32(A0,  pbv + 0*BSTR,  v); DOT32(A1,  pbv + 1*BSTR,  v);
            DOT32(A2,  pbv + 2*BSTR,  v); DOT32(A3,  pbv + 3*BSTR,  v);
            DOT32(A4,  pbv + 4*BSTR,  v); DOT32(A5,  pbv + 5*BSTR,  v);
            DOT32(A6,  pbv + 6*BSTR,  v); DOT32(A7,  pbv + 7*BSTR,  v);
            DOT32(A8,  pbv + 8*BSTR,  v); DOT32(A9,  pbv + 9*BSTR,  v);
            DOT32(A10, pbv + 10*BSTR, v); DOT32(A11, pbv + 11*BSTR, v);
            DOT32(A12, pbv + 12*BSTR, v); DOT32(A13, pbv + 13*BSTR, v);
            DOT32(A14, pbv + 14*BSTR, v); DOT32(A15, pbv + 15*BSTR, v);
        }
        BFLY(A0)  BFLY(A1)  BFLY(A2)  BFLY(A3)  BFLY(A4)  BFLY(A5)  BFLY(A6)  BFLY(A7)
        BFLY(A8)  BFLY(A9)  BFLY(A10) BFLY(A11) BFLY(A12) BFLY(A13) BFLY(A14) BFLY(A15)

        const int q = t + 1;
        const unsigned phO = 1u ^ (((unsigned)(q - 1) >> 2) & 1u);
        const unsigned phP = 1u ^ (((unsigned)t >> 6) & 1u);

        if (pub) {
            float y0, y1, y2, y3, y4, y5, y6, y7, y8, y9, y10, y11, y12, y13, y14, y15;
            if (l == 0) {
                y0  = fmaxf(A0  + XPB[sl][0*32  + rl], 0.f);
                y1  = fmaxf(A1  + XPB[sl][1*32  + rl], 0.f);
                y2  = fmaxf(A2  + XPB[sl][2*32  + rl], 0.f);
                y3  = fmaxf(A3  + XPB[sl][3*32  + rl], 0.f);
                y4  = fmaxf(A4  + XPB[sl][4*32  + rl], 0.f);
                y5  = fmaxf(A5  + XPB[sl][5*32  + rl], 0.f);
                y6  = fmaxf(A6  + XPB[sl][6*32  + rl], 0.f);
                y7  = fmaxf(A7  + XPB[sl][7*32  + rl], 0.f);
                y8  = fmaxf(A8  + XPB[sl][8*32  + rl], 0.f);
                y9  = fmaxf(A9  + XPB[sl][9*32  + rl], 0.f);
                y10 = fmaxf(A10 + XPB[sl][10*32 + rl], 0.f);
                y11 = fmaxf(A11 + XPB[sl][11*32 + rl], 0.f);
                y12 = fmaxf(A12 + XPB[sl][12*32 + rl], 0.f);
                y13 = fmaxf(A13 + XPB[sl][13*32 + rl], 0.f);
                y14 = fmaxf(A14 + XPB[sl][14*32 + rl], 0.f);
                y15 = fmaxf(A15 + XPB[sl][15*32 + rl], 0.f);
            } else {
                y0  = fmaxf(A0  + bias, 0.f); y1  = fmaxf(A1  + bias, 0.f);
                y2  = fmaxf(A2  + bias, 0.f); y3  = fmaxf(A3  + bias, 0.f);
                y4  = fmaxf(A4  + bias, 0.f); y5  = fmaxf(A5  + bias, 0.f);
                y6  = fmaxf(A6  + bias, 0.f); y7  = fmaxf(A7  + bias, 0.f);
                y8  = fmaxf(A8  + bias, 0.f); y9  = fmaxf(A9  + bias, 0.f);
                y10 = fmaxf(A10 + bias, 0.f); y11 = fmaxf(A11 + bias, 0.f);
                y12 = fmaxf(A12 + bias, 0.f); y13 = fmaxf(A13 + bias, 0.f);
                y14 = fmaxf(A14 + bias, 0.f); y15 = fmaxf(A15 + bias, 0.f);
            }
            if (q < TT) {
                unsigned long long* op = ob + (size_t)(q & 3) * 4096 + (size_t)R * 8;
                __hip_atomic_store(op+0, PK(y0,y1,phO),   __ATOMIC_RELAXED, __HIP_MEMORY_SCOPE_AGENT);
                __hip_atomic_store(op+1, PK(y2,y3,phO),   __ATOMIC_RELAXED, __HIP_MEMORY_SCOPE_AGENT);
                __hip_atomic_store(op+2, PK(y4,y5,phO),   __ATOMIC_RELAXED, __HIP_MEMORY_SCOPE_AGENT);
                __hip_atomic_store(op+3, PK(y6,y7,phO),   __ATOMIC_RELAXED, __HIP_MEMORY_SCOPE_AGENT);
                __hip_atomic_store(op+4, PK(y8,y9,phO),   __ATOMIC_RELAXED, __HIP_MEMORY_SCOPE_AGENT);
                __hip_atomic_store(op+5, PK(y10,y11,phO), __ATOMIC_RELAXED, __HIP_MEMORY_SCOPE_AGENT);
                __hip_atomic_store(op+6, PK(y12,y13,phO), __ATOMIC_RELAXED, __HIP_MEMORY_SCOPE_AGENT);
                __hip_atomic_store(op+7, PK(y14,y15,phO), __ATOMIC_RELAXED, __HIP_MEMORY_SCOPE_AGENT);
                // self-bypass: own row straight into next LDS buffer
                const int qs = q & 1;
                HY[qs][0][selfw]=y0;   HY[qs][1][selfw]=y1;   HY[qs][2][selfw]=y2;
                HY[qs][3][selfw]=y3;   HY[qs][4][selfw]=y4;   HY[qs][5][selfw]=y5;
                HY[qs][6][selfw]=y6;   HY[qs][7][selfw]=y7;   HY[qs][8][selfw]=y8;
                HY[qs][9][selfw]=y9;   HY[qs][10][selfw]=y10; HY[qs][11][selfw]=y11;
                HY[qs][12][selfw]=y12; HY[qs][13][selfw]=y13; HY[qs][14][selfw]=y14;
                HY[qs][15][selfw]=y15;
            }
            if (l < 2) {
                unsigned long long* pp = pbw + (size_t)(t & 63) * 4096 + (size_t)R * 8;
                __hip_atomic_store(pp+0, PK(y0,y1,phP),   __ATOMIC_RELAXED, __HIP_MEMORY_SCOPE_AGENT);
                __hip_atomic_store(pp+1, PK(y2,y3,phP),   __ATOMIC_RELAXED, __HIP_MEMORY_SCOPE_AGENT);
                __hip_atomic_store(pp+2, PK(y4,y5,phP),   __ATOMIC_RELAXED, __HIP_MEMORY_SCOPE_AGENT);
                __hip_atomic_store(pp+3, PK(y6,y7,phP),   __ATOMIC_RELAXED, __HIP_MEMORY_SCOPE_AGENT);
                __hip_atomic_store(pp+4, PK(y8,y9,phP),   __ATOMIC_RELAXED, __HIP_MEMORY_SCOPE_AGENT);
                __hip_atomic_store(pp+5, PK(y10,y11,phP), __ATOMIC_RELAXED, __HIP_MEMORY_SCOPE_AGENT);
                __hip_atomic_store(pp+6, PK(y12,y13,phP), __ATOMIC_RELAXED, __HIP_MEMORY_SCOPE_AGENT);
                __hip_atomic_store(pp+7, PK(y14,y15,phP), __ATOMIC_RELAXED, __HIP_MEMORY_SCOPE_AGENT);
            }
            if (l == 2 && t == TT - 1) {
                yfinal[(size_t)(g*16+0)*HH+R]=y0;   yfinal[(size_t)(g*16+1)*HH+R]=y1;
                yfinal[(size_t)(g*16+2)*HH+R]=y2;   yfinal[(size_t)(g*16+3)*HH+R]=y3;
                yfinal[(size_t)(g*16+4)*HH+R]=y4;   yfinal[(size_t)(g*16+5)*HH+R]=y5;
                yfinal[(size_t)(g*16+6)*HH+R]=y6;   yfinal[(size_t)(g*16+7)*HH+R]=y7;
                yfinal[(size_t)(g*16+8)*HH+R]=y8;   yfinal[(size_t)(g*16+9)*HH+R]=y9;
                yfinal[(size_t)(g*16+10)*HH+R]=y10; yfinal[(size_t)(g*16+11)*HH+R]=y11;
                yfinal[(size_t)(g*16+12)*HH+R]=y12; yfinal[(size_t)(g*16+13)*HH+R]=y13;
                yfinal[(size_t)(g*16+14)*HH+R]=y14; yfinal[(size_t)(g*16+15)*HH+R]=y15;
            }
        }

        if (q < TT) {
            // xp prefetch (l==0, ALL threads): ISSUE BEFORE POLLS (R6 lesson);
            // the ds_write lands after the poll, latency hidden in the spin.
            float xv = 0.f;
            if (l == 0)
                xv = XP[((size_t)(g * 16 + (tid >> 5)) * TT + q) * HH + s * 32 + (tid & 31)];

            if (!selfrow) {   // own-layer poll (row tid)
                unsigned long long* op = ob + (size_t)(q & 3) * 4096 + (size_t)tid * 8;
                unsigned long long u0, u1, u2, u3, u4, u5, u6, u7;
                for (;;) {
                    u0 = __hip_atomic_load(op+0, __ATOMIC_RELAXED, __HIP_MEMORY_SCOPE_AGENT);
                    u1 = __hip_atomic_load(op+1, __ATOMIC_RELAXED, __HIP_MEMORY_SCOPE_AGENT);
                    u2 = __hip_atomic_load(op+2, __ATOMIC_RELAXED, __HIP_MEMORY_SCOPE_AGENT);
                    u3 = __hip_atomic_load(op+3, __ATOMIC_RELAXED, __HIP_MEMORY_SCOPE_AGENT);
                    u4 = __hip_atomic_load(op+4, __ATOMIC_RELAXED, __HIP_MEMORY_SCOPE_AGENT);
                    u5 = __hip_atomic_load(op+5, __ATOMIC_RELAXED, __HIP_MEMORY_SCOPE_AGENT);
                    u6 = __hip_atomic_load(op+6, __ATOMIC_RELAXED, __HIP_MEMORY_SCOPE_AGENT);
                    u7 = __hip_atomic_load(op+7, __ATOMIC_RELAXED, __HIP_MEMORY_SCOPE_AGENT);
                    if ((BAD(u0,phO)|BAD(u1,phO)|BAD(u2,phO)|BAD(u3,phO)|
                         BAD(u4,phO)|BAD(u5,phO)|BAD(u6,phO)|BAD(u7,phO)) == 0u) break;
                }
                const int qs = q & 1;
                UNP(HY, qs, 0, u0) UNP(HY, qs, 1, u1) UNP(HY, qs, 2, u2) UNP(HY, qs, 3, u3)
                UNP(HY, qs, 4, u4) UNP(HY, qs, 5, u5) UNP(HY, qs, 6, u6) UNP(HY, qs, 7, u7)
            }
            if (l > 0) {      // prev-layer poll for step q (row tid)
                const unsigned phQ = 1u ^ (((unsigned)q >> 6) & 1u);
                unsigned long long* pp = pbr + (size_t)(q & 63) * 4096 + (size_t)tid * 8;
                unsigned long long u0, u1, u2, u3, u4, u5, u6, u7;
                for (;;) {
                    u0 = __hip_atomic_load(pp+0, __ATOMIC_RELAXED, __HIP_MEMORY_SCOPE_AGENT);
                    u1 = __hip_atomic_load(pp+1, __ATOMIC_RELAXED, __HIP_MEMORY_SCOPE_AGENT);
                    u2 = __hip_atomic_load(pp+2, __ATOMIC_RELAXED, __HIP_MEMORY_SCOPE_AGENT);
                    u3 = __hip_atomic_load(pp+3, __ATOMIC_RELAXED, __HIP_MEMORY_SCOPE_AGENT);
                    u4 = __hip_atomic_load(pp+4, __ATOMIC_RELAXED, __HIP_MEMORY_SCOPE_AGENT);
                    u5 = __hip_atomic_load(pp+5, __ATOMIC_RELAXED, __HIP_MEMORY_SCOPE_AGENT);
                    u6 = __hip_atomic_load(pp+6, __ATOMIC_RELAXED, __HIP_MEMORY_SCOPE_AGENT);
                    u7 = __hip_atomic_load(pp+7, __ATOMIC_RELAXED, __HIP_MEMORY_SCOPE_AGENT);
                    if ((BAD(u0,phQ)|BAD(u1,phQ)|BAD(u2,phQ)|BAD(u3,phQ)|
                         BAD(u4,phQ)|BAD(u5,phQ)|BAD(u6,phQ)|BAD(u7,phQ)) == 0u) break;
                }
                const int qs = q & 1;
                UNP(PY, qs, 0, u0) UNP(PY, qs, 1, u1) UNP(PY, qs, 2, u2) UNP(PY, qs, 3, u3)
                UNP(PY, qs, 4, u4) UNP(PY, qs, 5, u5) UNP(PY, qs, 6, u6) UNP(PY, qs, 7, u7)
            }
            if (l == 0) XPB[q & 1][tid] = xv;

            __threadfence_block();   // chunk writes visible before flag
            if (lane == 0)
                __hip_atomic_store(&written[wv], q, __ATOMIC_RELAXED, __HIP_MEMORY_SCOPE_WORKGROUP);
        }
    }
#undef PK
#undef BAD
#undef UNP
#undef FMA4
#undef DOT32
#undef BFLY
}

// ---------------------------------------------------------------------------
// Head: out[b][c] = yfinal[b][:]·W_out[c][:] + b_out[c]
// ---------------------------------------------------------------------------
__global__ __launch_bounds__(64) void head_kernel(
    const float* __restrict__ yfinal, const float* __restrict__ Wout,
    const float* __restrict__ bout, float* __restrict__ out)
{
    const int bc = blockIdx.x;
    const int b = bc / CC, c = bc % CC;
    const int lane = threadIdx.x;
    const float* yrow = yfinal + (size_t)b * HH;
    const float* wrow = Wout + (size_t)c * HH;
    float s = 0.f;
#pragma unroll
    for (int i = 0; i < HH / 64; ++i)
        s = fmaf(yrow[lane + 64 * i], wrow[lane + 64 * i], s);
#pragma unroll
    for (int off = 32; off > 0; off >>= 1) s += __shfl_down(s, off);
    if (lane == 0) out[bc] = s + bout[c];
}

// ---------------------------------------------------------------------------
extern "C" void kernel_launch(void* const* d_in, const int* in_sizes, int n_in,
                              void* d_out, int out_size, void* d_ws, size_t ws_size,
                              hipStream_t stream)
{
    const float* x = (const float*)d_in[0];
    const float* W_ih[3] = {(const float*)d_in[1], (const float*)d_in[5], (const float*)d_in[9]};
    const float* W_hh[3] = {(const float*)d_in[2], (const float*)d_in[6], (const float*)d_in[10]};
    const float* b_ih[3] = {(const float*)d_in[3], (const float*)d_in[7], (const float*)d_in[11]};
    const float* b_hh[3] = {(const float*)d_in[4], (const float*)d_in[8], (const float*)d_in[12]};
    const float* W_out = (const float*)d_in[13];
    const float* b_out = (const float*)d_in[14];
    float* out = (float*)d_out;

    // workspace: XP (67MB) | yfinal (128KB) | obuf (1.5MB) | pbuf (16MB) | ack
    float* ws = (float*)d_ws;
    float* XP = ws;
    float* yfinal = ws + (size_t)BB * TT * HH;
    unsigned long long* obuf = (unsigned long long*)(yfinal + (size_t)BB * HH);
    // obuf: 12 (l,g) x 16384 u64
    unsigned long long* pbuf = obuf + (size_t)12 * 16384;
    // pbuf: 8 (iface,g) x 262144 u64
    int* ack = (int*)(pbuf + (size_t)8 * 262144);   // 2*4*16 ints

    const size_t zero_bytes = ((size_t)12 * 16384 + (size_t)8 * 262144) * 8
                            + (size_t)2 * 4 * 16 * sizeof(int);
    (void)hipMemsetAsync(obuf, 0, zero_bytes, stream);

    // layer-0 input projection
    gemm_bias_kernel<<<dim3(256, 4), 256, 0, stream>>>(x, W_ih[0], b_ih[0], b_hh[0], XP, II);
    // fused 3-layer wavefront pipeline (192 blocks, all co-resident at 1/CU)
    rnn_pipeline_kernel<<<192, 512, 0, stream>>>(
        XP, W_hh[0], W_hh[1], W_hh[2], W_ih[1], W_ih[2],
        b_ih[1], b_hh[1], b_ih[2], b_hh[2], yfinal, obuf, pbuf, ack);
    // head
    head_kernel<<<BB * CC, 64, 0, stream>>>(yfinal, W_out, b_out, out);
}